// Round 14
// baseline (1851.659 us; speedup 1.0000x reference)
//
#include <hip/hip_runtime.h>
#include <cstdint>
#include <cstddef>

typedef _Float16 f16;
typedef _Float16 f16x4 __attribute__((ext_vector_type(4)));
typedef _Float16 f16x8 __attribute__((ext_vector_type(8)));
typedef float f32x4 __attribute__((ext_vector_type(4)));

// ---------- sizes ----------
#define SEQ 1024
#define BATCH 128
#define INDIM 256
#define HDIM 512
#define MROWS (SEQ * BATCH)          // 131072
#define NCOLS (3 * HDIM)             // 1536
#define BHDIM (BATCH * HDIM)         // 65536
#define TCHUNK 256
#define CHROWS (TCHUNK * BATCH)      // 32768
#define NCH (SEQ / TCHUNK)           // 4

// workspace layout (bytes); total 473,176,064 < 506,730,496 proven available
#define P32_OFF   0ull                         // [32768][1536] f32 = 201,326,592
#define Y0_OFF    201326592ull                 // [131072][512] f32 = 268,435,456
#define WHI_OFF   469762048ull                 // [1536][512] f16   = 1,572,864
#define WLO_OFF   471334912ull                 // [1536][512] f16   = 1,572,864
#define BIAS_OFF  472907776ull                 // [1536] f32        = 6,144
#define HST_OFF   472913920ull                 // [65536] f32       = 262,144
#define WS_NEEDED 473176064ull

__device__ __forceinline__ float fast_tanh(float x) {
  return 1.0f - 2.0f / (__expf(2.0f * x) + 1.0f);
}
__device__ __forceinline__ float fast_sigmoid(float x) {
  return 1.0f / (1.0f + __expf(-x));
}

__device__ __forceinline__ void split4(const float* __restrict__ in, f16* __restrict__ hi,
                                       f16* __restrict__ lo, int i) {
  float4 v = reinterpret_cast<const float4*>(in)[i];
  f16x4 h4 = {(f16)v.x, (f16)v.y, (f16)v.z, (f16)v.w};
  f16x4 l4 = {(f16)((v.x - (float)h4[0]) * 2048.0f),
              (f16)((v.y - (float)h4[1]) * 2048.0f),
              (f16)((v.z - (float)h4[2]) * 2048.0f),
              (f16)((v.w - (float)h4[3]) * 2048.0f)};
  reinterpret_cast<f16x4*>(hi)[i] = h4;
  reinterpret_cast<f16x4*>(lo)[i] = l4;
}

// ---------- consolidated prep: 3 weight splits + 3 bias copies (one dispatch) ----------
__global__ __launch_bounds__(256) void prep_kernel(
    const float* __restrict__ w0, const float* __restrict__ w1, const float* __restrict__ w2,
    f16* __restrict__ wh, f16* __restrict__ wl, int n4w,
    const float* __restrict__ b0, const float* __restrict__ b1, const float* __restrict__ b2,
    float* __restrict__ bias, int nb4) {
  const int total = 3 * n4w + 3 * nb4;
  const int stride = gridDim.x * blockDim.x;
  for (int i = blockIdx.x * blockDim.x + threadIdx.x; i < total; i += stride) {
    if (i < 3 * n4w) {
      int m = i / n4w;
      int off = i - m * n4w;
      const float* src = (m == 0) ? w0 : ((m == 1) ? w1 : w2);
      split4(src, wh + (long)m * n4w * 4, wl + (long)m * n4w * 4, off);
    } else {
      int k = i - 3 * n4w;
      int m = k / nb4;
      int off = k - m * nb4;
      const float* src = (m == 0) ? b0 : ((m == 1) ? b1 : b2);
      reinterpret_cast<float4*>(bias)[m * nb4 + off] =
          reinterpret_cast<const float4*>(src)[off];
    }
  }
}

// ---------- GEMM: P[CHROWS,1536](f32) = (split(A_f32)).(Whi+Wlo/2048)^T + bias ----------
// r13 structure (T14 reg-staged dbuf, one sync/K-step, 16x16x32 MFMA, inline A-split)
// with FRAGMENT-ORDERED LDS: tile byte addr(row,k) = (row>>4)*1024 +
// ((k>>3)*16 + (row&15))*16 + (k&7)*2.  MFMA frag read = base + lane*16 (wave-linear
// 1024B, 0 conflicts); staging write = unit*16 (wave-linear, 0 conflicts).  r13's
// padded layout had 8-lane same-bank read chains (2.5e7 conflict counter) making LDS
// the binding pipe (~2500 cyc vs MFMA 1862 cyc per CU per K-step).
__global__ __launch_bounds__(256, 2) void gemm_split_kernel(
    const float* __restrict__ A,
    const f16* __restrict__ Whi, const f16* __restrict__ Wlo,
    const float* __restrict__ bias, float* __restrict__ P, int K) {
  constexpr int BK = 32;
  // 8KB per tile = 4096 f16; group = 16 rows = 512 f16 (1024 B)
  __shared__ f16 sAh[2][4096];
  __shared__ f16 sAl[2][4096];
  __shared__ f16 sBh[2][4096];
  __shared__ f16 sBl[2][4096];

  const int tid = threadIdx.x;
  const int lane = tid & 63;
  const int w = tid >> 6;
  const int wm = (w >> 1) * 64;
  const int wn = (w & 1) * 64;
  const int wmg = wm >> 4;          // frag group base (0 or 4)
  const int wng = wn >> 4;

  // XCD-aware bijective swizzle (gridDim.x = 3072, %8 == 0), n-block fastest
  const int per = gridDim.x >> 3;
  const int logical = (blockIdx.x & 7) * per + (blockIdx.x >> 3);
  const int nb = logical % (NCOLS / 128);
  const int mb = logical / (NCOLS / 128);
  const long m0 = (long)mb * 128;
  const int n0 = nb * 128;

  // staging units: u = r*256 + tid (r=0,1). Inverse map of the fragment-ordered layout:
  // row = (u>>6)*16 + (u&15), k = ((u>>4)&3)*8 (+0..7); LDS f16 index = u*8.
  const int u0 = tid, u1 = tid + 256;
  const int r0w = (u0 >> 6) * 16 + (u0 & 15), k0w = ((u0 >> 4) & 3) * 8;
  const int r1w = (u1 >> 6) * 16 + (u1 & 15), k1w = ((u1 >> 4) & 3) * 8;
  const long ga0 = (m0 + r0w) * (long)K + k0w;
  const long ga1 = (m0 + r1w) * (long)K + k1w;
  const long gb0 = (n0 + r0w) * (long)K + k0w;
  const long gb1 = (n0 + r1w) * (long)K + k1w;
  const int l0 = u0 * 8, l1 = u1 * 8;
  const int lb = lane * 8;          // frag read offset (f16) within group

  f32x4 acc[4][4] = {};
  f32x4 accc[4][4] = {};

  const int NT = K / BK;

  float4 rA0a, rA0b, rA1a, rA1b;
  f16x8 rBh0, rBh1, rBl0, rBl1;

#define LOADR(tt)                                                              \
  do {                                                                         \
    const int k0 = (tt) * BK;                                                  \
    rA0a = *reinterpret_cast<const float4*>(A + ga0 + k0);                     \
    rA0b = *reinterpret_cast<const float4*>(A + ga0 + k0 + 4);                 \
    rA1a = *reinterpret_cast<const float4*>(A + ga1 + k0);                     \
    rA1b = *reinterpret_cast<const float4*>(A + ga1 + k0 + 4);                 \
    rBh0 = *reinterpret_cast<const f16x8*>(Whi + gb0 + k0);                    \
    rBh1 = *reinterpret_cast<const f16x8*>(Whi + gb1 + k0);                    \
    rBl0 = *reinterpret_cast<const f16x8*>(Wlo + gb0 + k0);                    \
    rBl1 = *reinterpret_cast<const f16x8*>(Wlo + gb1 + k0);                    \
  } while (0)
#define SPLIT8(va, vb, h8, l8)                                                 \
  f16x8 h8 = {(f16)va.x, (f16)va.y, (f16)va.z, (f16)va.w,                      \
              (f16)vb.x, (f16)vb.y, (f16)vb.z, (f16)vb.w};                     \
  f16x8 l8 = {(f16)((va.x - (float)h8[0]) * 2048.0f),                          \
              (f16)((va.y - (float)h8[1]) * 2048.0f),                          \
              (f16)((va.z - (float)h8[2]) * 2048.0f),                          \
              (f16)((va.w - (float)h8[3]) * 2048.0f),                          \
              (f16)((vb.x - (float)h8[4]) * 2048.0f),                          \
              (f16)((vb.y - (float)h8[5]) * 2048.0f),                          \
              (f16)((vb.z - (float)h8[6]) * 2048.0f),                          \
              (f16)((vb.w - (float)h8[7]) * 2048.0f)}
#define WRITEB(buf)                                                            \
  do {                                                                         \
    SPLIT8(rA0a, rA0b, h80, l80);                                              \
    SPLIT8(rA1a, rA1b, h81, l81);                                              \
    *reinterpret_cast<f16x8*>(&sAh[(buf)][l0]) = h80;                          \
    *reinterpret_cast<f16x8*>(&sAl[(buf)][l0]) = l80;                          \
    *reinterpret_cast<f16x8*>(&sAh[(buf)][l1]) = h81;                          \
    *reinterpret_cast<f16x8*>(&sAl[(buf)][l1]) = l81;                          \
    *reinterpret_cast<f16x8*>(&sBh[(buf)][l0]) = rBh0;                         \
    *reinterpret_cast<f16x8*>(&sBh[(buf)][l1]) = rBh1;                         \
    *reinterpret_cast<f16x8*>(&sBl[(buf)][l0]) = rBl0;                         \
    *reinterpret_cast<f16x8*>(&sBl[(buf)][l1]) = rBl1;                         \
  } while (0)

  LOADR(0);
  WRITEB(0);
  __syncthreads();

  int cur = 0;
  for (int t = 0; t < NT; ++t) {
    const bool pf = (t + 1) < NT;
    if (pf) LOADR(t + 1);  // issue early; vmcnt wait lands after the MFMA cluster

    f16x8 ah[4], al[4], bh[4], bl[4];
#pragma unroll
    for (int i = 0; i < 4; ++i) {
      ah[i] = *reinterpret_cast<const f16x8*>(&sAh[cur][(wmg + i) * 512 + lb]);
      al[i] = *reinterpret_cast<const f16x8*>(&sAl[cur][(wmg + i) * 512 + lb]);
      bh[i] = *reinterpret_cast<const f16x8*>(&sBh[cur][(wng + i) * 512 + lb]);
      bl[i] = *reinterpret_cast<const f16x8*>(&sBl[cur][(wng + i) * 512 + lb]);
    }

    __builtin_amdgcn_s_setprio(1);
#pragma unroll
    for (int i = 0; i < 4; ++i)
#pragma unroll
      for (int j = 0; j < 4; ++j) {
        acc[i][j]  = __builtin_amdgcn_mfma_f32_16x16x32_f16(ah[i], bh[j], acc[i][j], 0, 0, 0);
        accc[i][j] = __builtin_amdgcn_mfma_f32_16x16x32_f16(ah[i], bl[j], accc[i][j], 0, 0, 0);
        accc[i][j] = __builtin_amdgcn_mfma_f32_16x16x32_f16(al[i], bh[j], accc[i][j], 0, 0, 0);
      }
    __builtin_amdgcn_s_setprio(0);

    if (pf) {
      WRITEB(cur ^ 1);   // split in regs + linear ds_write (vmcnt auto-waited)
      __syncthreads();
      cur ^= 1;
    }
  }
#undef LOADR
#undef SPLIT8
#undef WRITEB

  // epilogue: C/D layout col = lane&15, row = (lane>>4)*4 + reg
  const int crow = (lane >> 4) * 4;
  const int ccol = lane & 15;
#pragma unroll
  for (int j = 0; j < 4; ++j) {
    int gc = n0 + wn + j * 16 + ccol;
    float bv = bias[gc];
#pragma unroll
    for (int i = 0; i < 4; ++i) {
      long gr = m0 + wm + i * 16 + crow;
#pragma unroll
      for (int r = 0; r < 4; ++r) {
        P[(gr + r) * NCOLS + gc] = acc[i][j][r] + accc[i][j][r] * (1.0f / 2048.0f) + bv;
      }
    }
  }
}

// ---------- BRC scan over one t-chunk: one thread per (b,h) chain ----------
// Y (and HN) pre-offset by the caller to this chunk's base.
__global__ __launch_bounds__(256) void scan_kernel(
    const float* __restrict__ P, const float* __restrict__ hinit,
    float* __restrict__ hstate, int first,
    const float* __restrict__ wc, const float* __restrict__ wa,
    float* __restrict__ Y, float* __restrict__ HN) {
  const int j = blockIdx.x * 256 + threadIdx.x;  // 0..65535
  const int hh = j & (HDIM - 1);
  float h = first ? hinit[j] : hstate[j];
  const float wcv = wc[hh];
  const float wav = wa[hh];
  const float* p = P + (long)(j >> 9) * NCOLS + hh;
  float* y = Y + j;
#pragma unroll 4
  for (int t = 0; t < TCHUNK; ++t) {
    float pc = p[0];
    float pa = p[HDIM];
    float ph = p[2 * HDIM];
    float c = fast_sigmoid(fmaf(wcv, h, pc));
    float a = 1.0f + fast_tanh(fmaf(wav, h, pa));
    h = c * h + (1.0f - c) * fast_tanh(fmaf(a, h, ph));
    *y = h;
    y += BHDIM;
    p += BATCH * NCOLS;
  }
  hstate[j] = h;
  if (HN) HN[j] = h;
}

extern "C" void kernel_launch(void* const* d_in, const int* in_sizes, int n_in,
                              void* d_out, int out_size, void* d_ws, size_t ws_size,
                              hipStream_t stream) {
  const float* x   = (const float*)d_in[0];
  const float* h0  = (const float*)d_in[1];
  const float* Uc0 = (const float*)d_in[2];
  const float* wc0 = (const float*)d_in[3];
  const float* bc0 = (const float*)d_in[4];
  const float* Ua0 = (const float*)d_in[5];
  const float* wa0 = (const float*)d_in[6];
  const float* ba0 = (const float*)d_in[7];
  const float* Uh0 = (const float*)d_in[8];
  const float* bh0 = (const float*)d_in[9];
  const float* Uc1 = (const float*)d_in[10];
  const float* wc1 = (const float*)d_in[11];
  const float* bc1 = (const float*)d_in[12];
  const float* Ua1 = (const float*)d_in[13];
  const float* wa1 = (const float*)d_in[14];
  const float* ba1 = (const float*)d_in[15];
  const float* Uh1 = (const float*)d_in[16];
  const float* bh1 = (const float*)d_in[17];

  if (ws_size < WS_NEEDED) return;

  char* ws = (char*)d_ws;
  float* p32  = (float*)(ws + P32_OFF);
  float* y0   = (float*)(ws + Y0_OFF);
  f16* whi    = (f16*)(ws + WHI_OFF);
  f16* wlo    = (f16*)(ws + WLO_OFF);
  float* bias = (float*)(ws + BIAS_OFF);
  float* hst  = (float*)(ws + HST_OFF);

  float* y1  = (float*)d_out;
  float* hn0 = y1 + (long)SEQ * BHDIM;
  float* hn1 = hn0 + BHDIM;

  const dim3 gemm_grid((CHROWS / 128) * (NCOLS / 128));  // 256*12 = 3072, %8==0

  // ---- prep 0: L0 weight splits + biases ----
  hipLaunchKernelGGL(prep_kernel, dim3(512), dim3(256), 0, stream,
                     Uc0, Ua0, Uh0, whi, wlo, HDIM * INDIM / 4,
                     bc0, ba0, bh0, bias, HDIM / 4);

  // ---- layer 0: chunked GEMM (A = x f32, inline split) + scan ----
  for (int tc = 0; tc < NCH; ++tc) {
    hipLaunchKernelGGL(gemm_split_kernel, gemm_grid, dim3(256), 0, stream,
                       x + (long)tc * CHROWS * INDIM, whi, wlo, bias, p32, INDIM);
    hipLaunchKernelGGL(scan_kernel, dim3(BHDIM / 256), dim3(256), 0, stream,
                       p32, h0, hst, (tc == 0) ? 1 : 0, wc0, wa0,
                       y0 + (long)tc * TCHUNK * BHDIM,
                       (tc == NCH - 1) ? hn0 : (float*)nullptr);
  }

  // ---- prep 1: L1 weight splits + biases ----
  hipLaunchKernelGGL(prep_kernel, dim3(512), dim3(256), 0, stream,
                     Uc1, Ua1, Uh1, whi, wlo, HDIM * HDIM / 4,
                     bc1, ba1, bh1, bias, HDIM / 4);

  // ---- layer 1: chunked GEMM (A = y0 f32, inline split) + scan ----
  for (int tc = 0; tc < NCH; ++tc) {
    hipLaunchKernelGGL(gemm_split_kernel, gemm_grid, dim3(256), 0, stream,
                       y0 + (long)tc * CHROWS * HDIM, whi, wlo, bias, p32, HDIM);
    hipLaunchKernelGGL(scan_kernel, dim3(BHDIM / 256), dim3(256), 0, stream,
                       p32, h0 + BHDIM, hst, (tc == 0) ? 1 : 0, wc1, wa1,
                       y1 + (long)tc * TCHUNK * BHDIM,
                       (tc == NCH - 1) ? hn1 : (float*)nullptr);
  }
}